// Round 6
// baseline (185.001 us; speedup 1.0000x reference)
//
#include <hip/hip_runtime.h>

#define D     2048
#define NEXP  4
#define BLK   256
#define NWAVE 4
#define NTOK  2
#define EPSV  1e-5f

// decode packed bf16 pair (low / high 16 bits of a uint)
__device__ __forceinline__ float bl(unsigned int u) {
    union { unsigned int x; float f; } v; v.x = u << 16; return v.f;
}
__device__ __forceinline__ float bh(unsigned int u) {
    union { unsigned int x; float f; } v; v.x = u & 0xffff0000u; return v.f;
}
// pack two f32 -> packed bf16 (RNE), src0 in low, src1 in high
__device__ __forceinline__ unsigned int pk2(float x, float y) {
    unsigned int r;
    asm volatile("v_cvt_pk_bf16_f32 %0, %1, %2" : "=v"(r) : "v"(x), "v"(y));
    return r;
}

// ---- weight transpose: Wt[c][d], c: 0-3 Wb, 4-7 Wm, 8-23 Wr(i*4+j) ----
__global__ __launch_bounds__(256) void wt_kernel(
    const float* __restrict__ Wb, const float* __restrict__ Wm,
    const float* __restrict__ Wr, float* __restrict__ Wt)
{
    int idx = blockIdx.x * 256 + threadIdx.x;      // 24*2048 = 192*256
    int c = idx / D;
    int d = idx % D;
    float v;
    if (c < 4)       v = Wb[d * 4 + c];
    else if (c < 8)  v = Wm[d * 4 + (c - 4)];
    else             v = Wr[d * 16 + (c - 8)];
    Wt[c * D + d] = v;
}

__global__ __launch_bounds__(BLK) void hc_kernel(
    const float* __restrict__ lo,      // [tok, D]
    const float* __restrict__ hs,      // [tok, NEXP, D]
    const float* __restrict__ Bm,      // [1, NEXP]
    const float* __restrict__ Am,      // [NEXP, 1]
    const float* __restrict__ Ar,      // [NEXP, NEXP]
    const float* __restrict__ s_alpha, // [NEXP, NEXP]
    const float* __restrict__ s_beta,  // [1, NEXP]
    const float* __restrict__ Wt,      // [24, D] transposed weights
    float* __restrict__ out)           // [tok, NEXP, D]
{
    __shared__ unsigned int h16[NTOK][NEXP][D / 2];   // 32 KB packed bf16
    __shared__ float red[NWAVE][NTOK * 2 * NEXP];     // 256 B
    __shared__ float stats[NTOK][2][NEXP];
    __shared__ float coef[NTOK][24];

    const int tid  = threadIdx.x;
    const int wave = tid >> 6;
    const int lane = tid & 63;
    const long tok0 = (long)blockIdx.x * NTOK;

    const float4* hs4[NTOK];
    const float4* lo4[NTOK];
    float4*       out4[NTOK];
    #pragma unroll
    for (int t = 0; t < NTOK; ++t) {
        hs4[t]  = (const float4*)(hs + (tok0 + t) * (long)(NEXP * D));
        lo4[t]  = (const float4*)(lo + (tok0 + t) * (long)D);
        out4[t] = (float4*)(out + (tok0 + t) * (long)(NEXP * D));
    }

    // ---- Phase 1: load both tokens' hidden rows, stats + packed-bf16 LDS stage ----
    float sum[NTOK][NEXP], sq[NTOK][NEXP];
    #pragma unroll
    for (int t = 0; t < NTOK; ++t)
        #pragma unroll
        for (int n = 0; n < NEXP; ++n) { sum[t][n] = 0.f; sq[t][n] = 0.f; }

    #pragma unroll
    for (int t = 0; t < NTOK; ++t) {
        #pragma unroll
        for (int n = 0; n < NEXP; ++n) {
            #pragma unroll
            for (int k = 0; k < 2; ++k) {
                int d4 = tid + BLK * k;
                float4 v = hs4[t][n * (D / 4) + d4];
                sum[t][n] += v.x + v.y + v.z + v.w;
                sq[t][n]  += v.x * v.x + v.y * v.y + v.z * v.z + v.w * v.w;
                uint2 p;
                p.x = pk2(v.x, v.y);
                p.y = pk2(v.z, v.w);
                ((uint2*)h16[t][n])[d4] = p;
            }
        }
    }
    // prefetch layer_output (used only in phase 3)
    float4 lpre[NTOK][2];
    #pragma unroll
    for (int t = 0; t < NTOK; ++t) {
        lpre[t][0] = lo4[t][tid];
        lpre[t][1] = lo4[t][tid + BLK];
    }

    // wave shfl-xor tree (16 values, pipelined)
    #pragma unroll
    for (int t = 0; t < NTOK; ++t)
        #pragma unroll
        for (int n = 0; n < NEXP; ++n) {
            #pragma unroll
            for (int off = 32; off > 0; off >>= 1) {
                sum[t][n] += __shfl_xor(sum[t][n], off, 64);
                sq[t][n]  += __shfl_xor(sq[t][n],  off, 64);
            }
        }
    if (lane == 0) {
        #pragma unroll
        for (int t = 0; t < NTOK; ++t)
            #pragma unroll
            for (int n = 0; n < NEXP; ++n) {
                red[wave][t * 8 + n]        = sum[t][n];
                red[wave][t * 8 + NEXP + n] = sq[t][n];
            }
    }
    __syncthreads();
    if (tid < NTOK * NEXP) {                       // 8 threads
        int t = tid >> 2, n = tid & 3;
        float s = 0.f, s2 = 0.f;
        #pragma unroll
        for (int w = 0; w < NWAVE; ++w) {
            s  += red[w][t * 8 + n];
            s2 += red[w][t * 8 + NEXP + n];
        }
        float m   = s * (1.f / D);
        float var = s2 * (1.f / D) - m * m;
        stats[t][0][n] = m;
        stats[t][1][n] = rsqrtf(var + EPSV);
    }
    __syncthreads();
    float mu[NTOK][NEXP], rs[NTOK][NEXP];
    #pragma unroll
    for (int t = 0; t < NTOK; ++t)
        #pragma unroll
        for (int n = 0; n < NEXP; ++n) { mu[t][n] = stats[t][0][n]; rs[t][n] = stats[t][1][n]; }

    // ---- Phase 2: wave w owns columns 6w..6w+5; each weight load serves BOTH tokens ----
    float acc[NTOK][6];
    #pragma unroll
    for (int t = 0; t < NTOK; ++t)
        #pragma unroll
        for (int c = 0; c < 6; ++c) acc[t][c] = 0.f;

    const int cbase = wave * 6;
    const float4* Wt4 = (const float4*)Wt;          // [24][512]

    #pragma unroll
    for (int p = 0; p < 8; ++p) {
        int d4 = p * 64 + lane;                     // lane-contiguous
        float4 hb[NTOK];
        #pragma unroll
        for (int t = 0; t < NTOK; ++t) {
            uint2 r0 = ((const uint2*)h16[t][0])[d4];
            uint2 r1 = ((const uint2*)h16[t][1])[d4];
            uint2 r2 = ((const uint2*)h16[t][2])[d4];
            uint2 r3 = ((const uint2*)h16[t][3])[d4];
            hb[t].x = 0.25f * ((bl(r0.x) - mu[t][0]) * rs[t][0] + (bl(r1.x) - mu[t][1]) * rs[t][1] +
                               (bl(r2.x) - mu[t][2]) * rs[t][2] + (bl(r3.x) - mu[t][3]) * rs[t][3]);
            hb[t].y = 0.25f * ((bh(r0.x) - mu[t][0]) * rs[t][0] + (bh(r1.x) - mu[t][1]) * rs[t][1] +
                               (bh(r2.x) - mu[t][2]) * rs[t][2] + (bh(r3.x) - mu[t][3]) * rs[t][3]);
            hb[t].z = 0.25f * ((bl(r0.y) - mu[t][0]) * rs[t][0] + (bl(r1.y) - mu[t][1]) * rs[t][1] +
                               (bl(r2.y) - mu[t][2]) * rs[t][2] + (bl(r3.y) - mu[t][3]) * rs[t][3]);
            hb[t].w = 0.25f * ((bh(r0.y) - mu[t][0]) * rs[t][0] + (bh(r1.y) - mu[t][1]) * rs[t][1] +
                               (bh(r2.y) - mu[t][2]) * rs[t][2] + (bh(r3.y) - mu[t][3]) * rs[t][3]);
        }
        #pragma unroll
        for (int c = 0; c < 6; ++c) {
            float4 w = Wt4[(cbase + c) * (D / 4) + d4];
            #pragma unroll
            for (int t = 0; t < NTOK; ++t)
                acc[t][c] += hb[t].x * w.x + hb[t].y * w.y + hb[t].z * w.z + hb[t].w * w.w;
        }
    }
    // wave-internal trees -> complete sums
    #pragma unroll
    for (int t = 0; t < NTOK; ++t)
        #pragma unroll
        for (int c = 0; c < 6; ++c) {
            #pragma unroll
            for (int off = 32; off > 0; off >>= 1)
                acc[t][c] += __shfl_xor(acc[t][c], off, 64);
        }
    if (lane == 0) {
        #pragma unroll
        for (int t = 0; t < NTOK; ++t)
            #pragma unroll
            for (int c = 0; c < 6; ++c) coef[t][cbase + c] = acc[t][c];
    }
    __syncthreads();
    if (tid < NTOK * 24) {                          // 48 threads
        int t = tid / 24, c = tid % 24;
        float tv = tanhf(coef[t][c]);
        float cv;
        if (c < 4) {
            cv = s_beta[c] * tv + Bm[c];
        } else if (c < 8) {
            int n = c - 4;
            cv = s_alpha[n * 4] * tv + Am[n];
        } else {
            int ij = c - 8;
            cv = s_alpha[ij] * tv + Ar[ij];
        }
        coef[t][c] = cv;
    }
    __syncthreads();

    // ---- Phase 3: outputs from packed-bf16 LDS + prefetched lo ----
    #pragma unroll
    for (int t = 0; t < NTOK; ++t) {
        float Bd[NEXP], Amd[NEXP], Ard[NEXP][NEXP];
        #pragma unroll
        for (int n = 0; n < NEXP; ++n) { Bd[n] = coef[t][n]; Amd[n] = coef[t][4 + n]; }
        #pragma unroll
        for (int i = 0; i < NEXP; ++i)
            #pragma unroll
            for (int j = 0; j < NEXP; ++j) Ard[i][j] = coef[t][8 + i * 4 + j];

        #pragma unroll
        for (int k = 0; k < 2; ++k) {
            int d4 = tid + BLK * k;
            float4 h[NEXP];
            #pragma unroll
            for (int n = 0; n < NEXP; ++n) {
                uint2 r = ((const uint2*)h16[t][n])[d4];
                h[n].x = bl(r.x); h[n].y = bh(r.x);
                h[n].z = bl(r.y); h[n].w = bh(r.y);
            }
            float4 l = lpre[t][k];

            float4 mx = {0.f, 0.f, 0.f, 0.f};
            #pragma unroll
            for (int n = 0; n < NEXP; ++n) {
                mx.x += Amd[n] * h[n].x; mx.y += Amd[n] * h[n].y;
                mx.z += Amd[n] * h[n].z; mx.w += Amd[n] * h[n].w;
            }
            #pragma unroll
            for (int i = 0; i < NEXP; ++i) {
                float4 o;
                o.x = Bd[i] * l.x + mx.x;
                o.y = Bd[i] * l.y + mx.y;
                o.z = Bd[i] * l.z + mx.z;
                o.w = Bd[i] * l.w + mx.w;
                #pragma unroll
                for (int j = 0; j < NEXP; ++j) {
                    o.x += Ard[i][j] * h[j].x;
                    o.y += Ard[i][j] * h[j].y;
                    o.z += Ard[i][j] * h[j].z;
                    o.w += Ard[i][j] * h[j].w;
                }
                out4[t][i * (D / 4) + d4] = o;
            }
        }
    }
}

extern "C" void kernel_launch(void* const* d_in, const int* in_sizes, int n_in,
                              void* d_out, int out_size, void* d_ws, size_t ws_size,
                              hipStream_t stream) {
    const float* lo      = (const float*)d_in[0];
    const float* hs      = (const float*)d_in[1];
    const float* Bm      = (const float*)d_in[2];
    const float* Am      = (const float*)d_in[3];
    const float* Ar      = (const float*)d_in[4];
    const float* s_alpha = (const float*)d_in[5];
    const float* s_beta  = (const float*)d_in[6];
    const float* Wb      = (const float*)d_in[7];
    const float* Wm      = (const float*)d_in[8];
    const float* Wr      = (const float*)d_in[9];
    float* out = (float*)d_out;
    float* Wt  = (float*)d_ws;                     // 196 608 B

    wt_kernel<<<192, 256, 0, stream>>>(Wb, Wm, Wr, Wt);

    const int tokens = in_sizes[0] / D;            // 8192
    hc_kernel<<<tokens / NTOK, BLK, 0, stream>>>(lo, hs, Bm, Am, Ar, s_alpha, s_beta,
                                                 Wt, out);
}

// Round 7
// 146.807 us; speedup vs baseline: 1.2602x; 1.2602x over previous
//
#include <hip/hip_runtime.h>
#include <hip/hip_fp16.h>

#define D     2048
#define BLK   512
#define EPSV  1e-5f

typedef _Float16 h2 __attribute__((ext_vector_type(2)));

__device__ __forceinline__ unsigned int pkh(float a, float b) {
    return __builtin_bit_cast(unsigned int, __builtin_amdgcn_cvt_pkrtz(a, b));
}
__device__ __forceinline__ h2 ash2(unsigned int u) {
    return __builtin_bit_cast(h2, u);
}

// ---- weight prep: Wq[c][p] = packed f16 pair of column c at d={2p,2p+1}; S[c] = sum_d w[c][d]
// c: 0-3 Wb, 4-7 Wm, 8-23 Wr(i*4+j). Grid: 24 blocks x 256 threads.
__global__ __launch_bounds__(256) void wt_kernel(
    const float* __restrict__ Wb, const float* __restrict__ Wm,
    const float* __restrict__ Wr, unsigned int* __restrict__ Wq,
    float* __restrict__ S)
{
    const int c = blockIdx.x;
    const int t = threadIdx.x;
    const float* src;
    int stride;
    if (c < 4)       { src = Wb + c;       stride = 4;  }
    else if (c < 8)  { src = Wm + (c - 4); stride = 4;  }
    else             { src = Wr + (c - 8); stride = 16; }

    float s = 0.f;
    #pragma unroll
    for (int k = 0; k < 4; ++k) {
        int p = t + 256 * k;                    // pair index 0..1023
        float a = src[(2 * p)     * stride];
        float b = src[(2 * p + 1) * stride];
        s += a + b;
        Wq[c * 1024 + p] = pkh(a, b);
    }
    __shared__ float rsum[4];
    #pragma unroll
    for (int off = 32; off; off >>= 1) s += __shfl_xor(s, off, 64);
    if ((t & 63) == 0) rsum[t >> 6] = s;
    __syncthreads();
    if (t == 0) S[c] = rsum[0] + rsum[1] + rsum[2] + rsum[3];
}

__global__ __launch_bounds__(BLK) void hc_kernel(
    const float* __restrict__ lo,      // [tok, D]
    const float* __restrict__ hs,      // [tok, 4, D]
    const float* __restrict__ Bm,      // [1,4]
    const float* __restrict__ Am,      // [4,1]
    const float* __restrict__ Ar,      // [4,4]
    const float* __restrict__ s_alpha, // [4,4]
    const float* __restrict__ s_beta,  // [1,4]
    const unsigned int* __restrict__ Wq, // [24][1024] packed f16 weight pairs
    const float* __restrict__ S,       // [24] column sums
    float* __restrict__ out)           // [tok, 4, D]
{
    __shared__ unsigned int hq[4][1024];   // 16 KB: f16-packed hidden rows
    __shared__ float Rl[24][4];            // raw dots R[c][n]
    __shared__ float sred[8][2];           // per-wave row-half {sum, sumsq}
    __shared__ float coefs[24];

    const int tid  = threadIdx.x;
    const int wave = tid >> 6;
    const int lane = tid & 63;
    const int row  = wave >> 1;            // wave pair per hidden row
    const int half = wave & 1;
    const long tok = blockIdx.x;

    const float4* hs4  = (const float4*)(hs + tok * (long)(4 * D));
    const float4* lo4  = (const float4*)(lo + tok * (long)D);
    float4*       out4 = (float4*)(out + tok * (long)(4 * D));

    // ---- Phase 1: wave loads its half-row (lane-contiguous float4), stats + f16 pack ----
    float4 hv[4];
    const int base = row * 512 + half * 256 + lane;
    #pragma unroll
    for (int k = 0; k < 4; ++k) hv[k] = hs4[base + 64 * k];
    float4 lv = lo4[tid];                  // 512 threads cover the lo row; used in phase 3

    float s = 0.f, q = 0.f;
    uint2* hq2w = (uint2*)hq[row];
    #pragma unroll
    for (int k = 0; k < 4; ++k) {
        float4 v = hv[k];
        s += v.x + v.y + v.z + v.w;
        q += v.x * v.x + v.y * v.y + v.z * v.z + v.w * v.w;
        uint2 p;
        p.x = pkh(v.x, v.y);
        p.y = pkh(v.z, v.w);
        hq2w[half * 256 + 64 * k + lane] = p;
    }
    #pragma unroll
    for (int off = 32; off; off >>= 1) {
        s += __shfl_xor(s, off, 64);
        q += __shfl_xor(q, off, 64);
    }
    if (lane == 0) { sred[wave][0] = s; sred[wave][1] = q; }
    __syncthreads();                       // barrier 1: hq ready

    // ---- Phase 2: raw dots R[n][c] via v_dot2_f32_f16; wave owns cols 3w..3w+2 ----
    float acc[3][4];
    #pragma unroll
    for (int j = 0; j < 3; ++j)
        #pragma unroll
        for (int n = 0; n < 4; ++n) acc[j][n] = 0.f;

    const int c0 = wave * 3;
    const uint2* Wq2 = (const uint2*)Wq;   // [24][512] uint2

    #pragma unroll
    for (int k = 0; k < 8; ++k) {
        int i = 64 * k + lane;             // uint2 index, lane-contiguous
        uint2 hr[4];
        #pragma unroll
        for (int n = 0; n < 4; ++n) hr[n] = ((const uint2*)hq[n])[i];
        uint2 wv[3];
        #pragma unroll
        for (int j = 0; j < 3; ++j) wv[j] = Wq2[(c0 + j) * 512 + i];
        #pragma unroll
        for (int j = 0; j < 3; ++j)
            #pragma unroll
            for (int n = 0; n < 4; ++n) {
                acc[j][n] = __builtin_amdgcn_fdot2(ash2(hr[n].x), ash2(wv[j].x), acc[j][n], false);
                acc[j][n] = __builtin_amdgcn_fdot2(ash2(hr[n].y), ash2(wv[j].y), acc[j][n], false);
            }
    }
    #pragma unroll
    for (int j = 0; j < 3; ++j)
        #pragma unroll
        for (int n = 0; n < 4; ++n) {
            #pragma unroll
            for (int off = 32; off; off >>= 1)
                acc[j][n] += __shfl_xor(acc[j][n], off, 64);
        }
    if (lane == 0) {
        #pragma unroll
        for (int j = 0; j < 3; ++j)
            #pragma unroll
            for (int n = 0; n < 4; ++n) Rl[c0 + j][n] = acc[j][n];
    }
    __syncthreads();                       // barrier 2: Rl + sred ready

    // ---- Combine: coef[c] = affine(tanh(0.25 * sum_n rs[n]*(R[n][c] - mu[n]*S[c]))) ----
    if (tid < 24) {
        int c = tid;
        float Sc = S[c];
        float raw = 0.f;
        #pragma unroll
        for (int n = 0; n < 4; ++n) {
            float ss = sred[2 * n][0] + sred[2 * n + 1][0];
            float qq = sred[2 * n][1] + sred[2 * n + 1][1];
            float m   = ss * (1.f / D);
            float var = qq * (1.f / D) - m * m;
            float r   = rsqrtf(var + EPSV);
            raw += r * (Rl[c][n] - m * Sc);
        }
        raw *= 0.25f;
        float t = tanhf(raw);
        float cv;
        if (c < 4) {
            cv = s_beta[c] * t + Bm[c];
        } else if (c < 8) {
            int n = c - 4;
            cv = s_alpha[n * 4] * t + Am[n];
        } else {
            int ij = c - 8;
            cv = s_alpha[ij] * t + Ar[ij];
        }
        coefs[c] = cv;
    }
    __syncthreads();                       // barrier 3: coefs ready

    float Bd[4], Amd[4], Ard[4][4];
    #pragma unroll
    for (int n = 0; n < 4; ++n) { Bd[n] = coefs[n]; Amd[n] = coefs[4 + n]; }
    #pragma unroll
    for (int i = 0; i < 4; ++i)
        #pragma unroll
        for (int j = 0; j < 4; ++j) Ard[i][j] = coefs[8 + i * 4 + j];

    // ---- Phase 3: outputs; thread tid owns float4 d4 = tid ----
    float4 h[4];
    #pragma unroll
    for (int n = 0; n < 4; ++n) {
        uint2 r = ((const uint2*)hq[n])[tid];
        h2 a = ash2(r.x), b = ash2(r.y);
        h[n].x = (float)a[0]; h[n].y = (float)a[1];
        h[n].z = (float)b[0]; h[n].w = (float)b[1];
    }
    float4 mx = {0.f, 0.f, 0.f, 0.f};
    #pragma unroll
    for (int n = 0; n < 4; ++n) {
        mx.x += Amd[n] * h[n].x; mx.y += Amd[n] * h[n].y;
        mx.z += Amd[n] * h[n].z; mx.w += Amd[n] * h[n].w;
    }
    #pragma unroll
    for (int i = 0; i < 4; ++i) {
        float4 o;
        o.x = Bd[i] * lv.x + mx.x;
        o.y = Bd[i] * lv.y + mx.y;
        o.z = Bd[i] * lv.z + mx.z;
        o.w = Bd[i] * lv.w + mx.w;
        #pragma unroll
        for (int j = 0; j < 4; ++j) {
            o.x += Ard[i][j] * h[j].x;
            o.y += Ard[i][j] * h[j].y;
            o.z += Ard[i][j] * h[j].z;
            o.w += Ard[i][j] * h[j].w;
        }
        out4[i * 512 + tid] = o;
    }
}

extern "C" void kernel_launch(void* const* d_in, const int* in_sizes, int n_in,
                              void* d_out, int out_size, void* d_ws, size_t ws_size,
                              hipStream_t stream) {
    const float* lo      = (const float*)d_in[0];
    const float* hs      = (const float*)d_in[1];
    const float* Bm      = (const float*)d_in[2];
    const float* Am      = (const float*)d_in[3];
    const float* Ar      = (const float*)d_in[4];
    const float* s_alpha = (const float*)d_in[5];
    const float* s_beta  = (const float*)d_in[6];
    const float* Wb      = (const float*)d_in[7];
    const float* Wm      = (const float*)d_in[8];
    const float* Wr      = (const float*)d_in[9];
    float* out = (float*)d_out;

    unsigned int* Wq = (unsigned int*)d_ws;            // 24*1024*4 = 98304 B
    float* S         = (float*)((char*)d_ws + 24 * 1024 * 4);  // 96 B

    wt_kernel<<<24, 256, 0, stream>>>(Wb, Wm, Wr, Wq, S);

    const int tokens = in_sizes[0] / D;                // 8192
    hc_kernel<<<tokens, BLK, 0, stream>>>(lo, hs, Bm, Am, Ar, s_alpha, s_beta,
                                          Wq, S, out);
}